// Round 1
// baseline (178.634 us; speedup 1.0000x reference)
//
#include <hip/hip_runtime.h>
#include <hip/hip_bf16.h>

#define SATF 10.0f

// fast sigmoid: native exp + native rcp. Saturates cleanly:
// x <= -90  -> expf(+90)=inf -> rcp(inf)=0  (matches fp32 sigmoid underflow)
// x >= +90  -> expf(-90)=0   -> rcp(1)=1
__device__ __forceinline__ float sigf(float x) {
    return __builtin_amdgcn_rcpf(1.0f + __expf(-x));
}

// One wave (64 lanes) per (batch b, pair p). Lane j holds position j's three
// channels (t0 = generate, t1 = carry/propagate, t2 = xor) in registers.
// P = number of output rows this stage (input has 2P rows of width 64).
// FUSE_FIRST: input is x (B x 64 bits); compute the first layer's rows
// 2p and 2p+1 on the fly via intra-wave shuffles.
template<int P, bool FUSE_FIRST, bool LAST>
__global__ __launch_bounds__(256) void stage_kernel(const float* __restrict__ in,
                                                    float* __restrict__ out,
                                                    int B) {
    const int gid  = (int)((blockIdx.x * blockDim.x + threadIdx.x) >> 6);
    const int lane = (int)(threadIdx.x & 63);
    if (gid >= B * P) return;
    const int b = gid / P;
    const int p = gid % P;

    float av, bv;
    if (FUSE_FIRST) {
        // x row: p = x[0:32], q = x[32:64]
        const float xv = in[b * 64 + lane];
        const int i0 = 2 * p, i1 = 2 * p + 1;
        const float q0 = __shfl(xv, 32 + i0);
        const float q1 = __shfl(xv, 32 + i1);
        const int ji0 = lane - i0;
        const int ji1 = lane - i1;
        const float pg0 = __shfl(xv, min(max(ji0, 0), 31));
        const float pg1 = __shfl(xv, min(max(ji1, 0), 31));
        const float pre_a = (ji0 >= 0 && ji0 < 32) ? (2.0f * (pg0 + q0) - 3.0f) : -1.0f;
        const float pre_b = (ji1 >= 0 && ji1 < 32) ? (2.0f * (pg1 + q1) - 3.0f) : -1.0f;
        av = sigf(SATF * pre_a);
        bv = sigf(SATF * pre_b);
    } else {
        av = in[((size_t)b * (2 * P) + 2 * p) * 64 + lane];
        bv = in[((size_t)b * (2 * P) + 2 * p + 1) * 64 + lane];
    }

    const float apb = av + bv;
    float t0 = sigf(SATF * (2.0f * apb - 3.0f));
    float t1 = sigf(SATF * (2.0f * apb - 1.0f));
    float t2 = sigf(SATF * (1.0f - 2.0f * apb));

    // sequential carry scan: 64 steps; step i injects nc into (i, ch1) and
    // xor into (i, ch2); everything else gets the sharpening map sig(s*(2t-1)).
    for (int i = 0; i < 64; ++i) {
        const int prev = (i == 0) ? 0 : (i - 1);
        const float c_prev = __shfl(t0, prev);
        const float p_prev = __shfl(t1, prev);
        const float p_cur  = __shfl(t1, i);
        const float nc = (i == 0) ? -1.0f
                                  : (2.0f * (c_prev + p_prev) - 5.0f + 4.0f * p_cur);
        const float xorv = 1.0f - 2.0f * (t0 + t2);   // lane i's own t0,t2
        const float pre0 = 2.0f * t0 - 1.0f;
        const float pre1 = (lane == i) ? nc   : (2.0f * t1 - 1.0f);
        const float pre2 = (lane == i) ? xorv : (2.0f * t2 - 1.0f);
        t0 = sigf(SATF * pre0);
        t1 = sigf(SATF * pre1);
        t2 = sigf(SATF * pre2);
    }

    // epilogue
    const float t0p = __shfl_up(t0, 1);
    const float t1p = __shfl_up(t1, 1);
    const float carry = (lane == 0) ? -1.0f : (-1.0f + 2.0f * (t0p + t1p));
    const float xc = t2;
    const float u1 = sigf(SATF * (1.0f - 4.0f * xc - 2.0f * carry));
    const float u2 = sigf(SATF * (-7.0f + 6.0f * xc + 2.0f * carry));
    float o = SATF * (1.0f - 2.0f * (u1 + u2));
    if (!LAST) o = sigf(o);
    out[((size_t)b * P + p) * 64 + lane] = o;
}

extern "C" void kernel_launch(void* const* d_in, const int* in_sizes, int n_in,
                              void* d_out, int out_size, void* d_ws, size_t ws_size,
                              hipStream_t stream) {
    const float* x = (const float*)d_in[0];
    float* out = (float*)d_out;
    const int B = in_sizes[0] / 64;   // 1024

    float* buf0 = (float*)d_ws;                       // holds up to B*16*64 floats (4 MB)
    float* buf1 = buf0 + (size_t)B * 16 * 64;         // holds up to B*8*64 floats (2 MB)

    const int threads = 256;  // 4 waves per block

    {   // stage 0 (fused first layer): x -> buf0 (B,16,64)
        int blocks = (B * 16 * 64 + threads - 1) / threads;
        hipLaunchKernelGGL((stage_kernel<16, true,  false>), dim3(blocks), dim3(threads), 0, stream, x,    buf0, B);
    }
    {   // stage 1: (B,16,64) -> (B,8,64)
        int blocks = (B * 8 * 64 + threads - 1) / threads;
        hipLaunchKernelGGL((stage_kernel<8,  false, false>), dim3(blocks), dim3(threads), 0, stream, buf0, buf1, B);
    }
    {   // stage 2: (B,8,64) -> (B,4,64)
        int blocks = (B * 4 * 64 + threads - 1) / threads;
        hipLaunchKernelGGL((stage_kernel<4,  false, false>), dim3(blocks), dim3(threads), 0, stream, buf1, buf0, B);
    }
    {   // stage 3: (B,4,64) -> (B,2,64)
        int blocks = (B * 2 * 64 + threads - 1) / threads;
        hipLaunchKernelGGL((stage_kernel<2,  false, false>), dim3(blocks), dim3(threads), 0, stream, buf0, buf1, B);
    }
    {   // stage 4 (last): (B,2,64) -> d_out (B,64), raw (no final sigmoid)
        int blocks = (B * 1 * 64 + threads - 1) / threads;
        hipLaunchKernelGGL((stage_kernel<1,  false, true >), dim3(blocks), dim3(threads), 0, stream, buf1, out,  B);
    }
}

// Round 2
// 51.746 us; speedup vs baseline: 3.4521x; 3.4521x over previous
//
#include <hip/hip_runtime.h>
#include <hip/hip_bf16.h>

// The reference network is a saturated-sigmoid (s=10) encoding of a binary
// circuit: first layer builds the 32 partial products q_i * (P << i) of a
// 32x32-bit multiply, and each "addition stage" is an exact 64-bit
// ripple-carry adder (t0=generate, t1=propagate->carry chain, t2=xor;
// epilogue sum = xor ^ carry_in). Every pre-activation has |arg| >= s, so all
// values sit within sigma(10)=4.5e-5 of binary and perturbations are damped
// by sigma' at every layer. Net function: out[b][j] = bit j of (P_b * Q_b)
// mapped to +10 / -10, where P_b = bits x[b][0:32], Q_b = x[b][32:64].
// Reference output differs from exact +-10 by <= 20*2*sigma(10) ~ 1.8e-3,
// far under the 0.2 absmax threshold.

__global__ __launch_bounds__(256) void mul_bits_kernel(const float* __restrict__ x,
                                                       float* __restrict__ out,
                                                       int B) {
    const int gid  = blockIdx.x * blockDim.x + threadIdx.x;
    const int row  = gid >> 6;          // batch row, one wave per row
    const int lane = gid & 63;          // output bit position
    if (row >= B) return;

    const float xv = x[(size_t)row * 64 + lane];
    const unsigned long long mask = __ballot(xv > 0.5f);   // bit j = x[row][j]
    const unsigned long long P = mask & 0xFFFFFFFFull;     // x[:, :32]
    const unsigned long long Q = mask >> 32;               // x[:, 32:]
    const unsigned long long prod = P * Q;                 // 32x32 -> 64 bit

    out[(size_t)row * 64 + lane] = ((prod >> lane) & 1ull) ? 10.0f : -10.0f;
}

extern "C" void kernel_launch(void* const* d_in, const int* in_sizes, int n_in,
                              void* d_out, int out_size, void* d_ws, size_t ws_size,
                              hipStream_t stream) {
    const float* x = (const float*)d_in[0];
    float* out = (float*)d_out;
    const int B = in_sizes[0] / 64;     // 1024

    const int threads = 256;            // 4 rows per block
    const int blocks  = (B * 64 + threads - 1) / threads;
    hipLaunchKernelGGL(mul_bits_kernel, dim3(blocks), dim3(threads), 0, stream,
                       x, out, B);
}